// Round 4
// baseline (232.070 us; speedup 1.0000x reference)
//
#include <hip/hip_runtime.h>
#include <hip/hip_bf16.h>

constexpr int kEmbed = 128;
constexpr int kBatch = 65536;
constexpr int kNeg   = 10;
constexpr float kEps = 1e-10f;

// 8 lanes per sample, NO grid-stride loop: 65536 samples x 8 lanes = 524288
// threads = 2048 blocks x 256. Lane `sub` owns columns [16*sub, 16*sub+16)
// (4x float4 = 64B contiguous per lane; a row's 512B is covered by 8 lanes).
// All 48 row-gather loads per sample issue right after one index-load hop,
// all 8192 waves resident at once -> maximal memory-level parallelism.
__global__ __launch_bounds__(256, 4) void sgns_loss_kernel(
    const float* __restrict__ tw,
    const float* __restrict__ cw,
    const int*   __restrict__ t,
    const int*   __restrict__ c,
    const int*   __restrict__ n,
    float*       __restrict__ out)
{
    const int tid = threadIdx.x;
    const int b   = (blockIdx.x * blockDim.x + tid) >> 3;
    const int sub = tid & 7;
    const int col = sub * 16;

    const int it = t[b];
    const int ic = c[b];
    int ni[kNeg];
    #pragma unroll
    for (int k = 0; k < kNeg; ++k) ni[k] = n[b * kNeg + k];

    const float4* vtp = reinterpret_cast<const float4*>(tw + (size_t)it * kEmbed + col);
    const float4 vt0 = vtp[0], vt1 = vtp[1], vt2 = vtp[2], vt3 = vtp[3];

    float s[kNeg + 1];

    {
        const float4* vcp = reinterpret_cast<const float4*>(cw + (size_t)ic * kEmbed + col);
        const float4 a = vcp[0], b4 = vcp[1], c4 = vcp[2], d4 = vcp[3];
        s[0] = vt0.x*a.x + vt0.y*a.y + vt0.z*a.z + vt0.w*a.w
             + vt1.x*b4.x + vt1.y*b4.y + vt1.z*b4.z + vt1.w*b4.w
             + vt2.x*c4.x + vt2.y*c4.y + vt2.z*c4.z + vt2.w*c4.w
             + vt3.x*d4.x + vt3.y*d4.y + vt3.z*d4.z + vt3.w*d4.w;
    }

    #pragma unroll
    for (int k = 0; k < kNeg; ++k) {
        const float4* vnp = reinterpret_cast<const float4*>(cw + (size_t)ni[k] * kEmbed + col);
        const float4 a = vnp[0], b4 = vnp[1], c4 = vnp[2], d4 = vnp[3];
        s[k + 1] = vt0.x*a.x + vt0.y*a.y + vt0.z*a.z + vt0.w*a.w
                 + vt1.x*b4.x + vt1.y*b4.y + vt1.z*b4.z + vt1.w*b4.w
                 + vt2.x*c4.x + vt2.y*c4.y + vt2.z*c4.z + vt2.w*c4.w
                 + vt3.x*d4.x + vt3.y*d4.y + vt3.z*d4.z + vt3.w*d4.w;
    }

    // Reduce each score across the 8-lane group (masks 4,2,1 stay in-group).
    #pragma unroll
    for (int k = 0; k < kNeg + 1; ++k) {
        float v = s[k];
        v += __shfl_xor(v, 4);
        v += __shfl_xor(v, 2);
        v += __shfl_xor(v, 1);
        s[k] = v;
    }

    // pos: log(sigmoid(s0)+eps); negs: log(sigmoid(-sk)+eps) = log(1/(1+e^{sk})+eps)
    float lb = __logf(1.0f / (1.0f + __expf(-s[0])) + kEps);
    #pragma unroll
    for (int k = 1; k < kNeg + 1; ++k)
        lb += __logf(1.0f / (1.0f + __expf(s[k])) + kEps);

    // One contribution per sample (sub==0 lane), then block reduce.
    float acc = (sub == 0) ? lb : 0.0f;
    #pragma unroll
    for (int m = 32; m >= 1; m >>= 1) acc += __shfl_xor(acc, m);

    __shared__ float wave_sum[4];
    if ((tid & 63) == 0) wave_sum[tid >> 6] = acc;
    __syncthreads();
    if (tid == 0) {
        const float s4 = wave_sum[0] + wave_sum[1] + wave_sum[2] + wave_sum[3];
        atomicAdd(out, s4 * (-1.0f / (float)kBatch));
    }
}

extern "C" void kernel_launch(void* const* d_in, const int* in_sizes, int n_in,
                              void* d_out, int out_size, void* d_ws, size_t ws_size,
                              hipStream_t stream) {
    const float* tw = (const float*)d_in[0];
    const float* cw = (const float*)d_in[1];
    const int*   t  = (const int*)d_in[2];
    const int*   c  = (const int*)d_in[3];
    const int*   n  = (const int*)d_in[4];
    float* out = (float*)d_out;

    // d_out is re-poisoned to 0xAA before every launch; zero it ourselves.
    hipMemsetAsync(out, 0, sizeof(float), stream);

    // 65536 samples x 8 lanes = 2048 blocks x 256 threads, one sample/group.
    sgns_loss_kernel<<<2048, 256, 0, stream>>>(tw, cw, t, c, n, out);
}

// Round 5
// 220.455 us; speedup vs baseline: 1.0527x; 1.0527x over previous
//
#include <hip/hip_runtime.h>
#include <hip/hip_bf16.h>

constexpr int kEmbed = 128;
constexpr int kBatch = 65536;
constexpr int kNeg   = 10;
constexpr float kEps = 1e-10f;

// 32 lanes per sample (lane l owns float4 at column 4l -> each row-gather
// instruction is 32 contiguous lanes x 16B = 512B, perfectly coalesced,
// same pattern as the 63us round-3 kernel) but NO grid-stride loop:
// 65536 samples x 32 lanes = 8192 blocks x 256 threads, one sample/group.
// Isolates coalescing (kept) from parallelism (maxed).
__global__ __launch_bounds__(256, 4) void sgns_loss_kernel(
    const float* __restrict__ tw,
    const float* __restrict__ cw,
    const int*   __restrict__ t,
    const int*   __restrict__ c,
    const int*   __restrict__ n,
    float*       __restrict__ out)
{
    const int tid  = threadIdx.x;
    const int lane = tid & 31;
    const int b    = (blockIdx.x * blockDim.x + tid) >> 5;

    const int it = t[b];
    const int ic = c[b];
    int ni[kNeg];
    #pragma unroll
    for (int k = 0; k < kNeg; ++k) ni[k] = n[b * kNeg + k];

    const float4 vt = *reinterpret_cast<const float4*>(tw + (size_t)it * kEmbed + 4 * lane);
    const float4 vc = *reinterpret_cast<const float4*>(cw + (size_t)ic * kEmbed + 4 * lane);

    float s[kNeg + 1];
    s[0] = vt.x * vc.x + vt.y * vc.y + vt.z * vc.z + vt.w * vc.w;

    #pragma unroll
    for (int k = 0; k < kNeg; ++k) {
        const float4 vn = *reinterpret_cast<const float4*>(
            cw + (size_t)ni[k] * kEmbed + 4 * lane);
        s[k + 1] = vt.x * vn.x + vt.y * vn.y + vt.z * vn.z + vt.w * vn.w;
    }

    // Butterfly reduce each score across the 32-lane group.
    #pragma unroll
    for (int k = 0; k < kNeg + 1; ++k) {
        float v = s[k];
        v += __shfl_xor(v, 16);
        v += __shfl_xor(v, 8);
        v += __shfl_xor(v, 4);
        v += __shfl_xor(v, 2);
        v += __shfl_xor(v, 1);
        s[k] = v;
    }

    // pos: log(sigmoid(s0)+eps); negs: log(sigmoid(-sk)+eps) = log(1/(1+e^{sk})+eps)
    float lb = __logf(1.0f / (1.0f + __expf(-s[0])) + kEps);
    #pragma unroll
    for (int k = 1; k < kNeg + 1; ++k)
        lb += __logf(1.0f / (1.0f + __expf(s[k])) + kEps);

    // One contribution per sample (lane 0 of each 32-lane group).
    float acc = (lane == 0) ? lb : 0.0f;
    #pragma unroll
    for (int m = 32; m >= 1; m >>= 1) acc += __shfl_xor(acc, m);

    __shared__ float wave_sum[4];
    if ((tid & 63) == 0) wave_sum[tid >> 6] = acc;
    __syncthreads();
    if (tid == 0) {
        const float s4 = wave_sum[0] + wave_sum[1] + wave_sum[2] + wave_sum[3];
        atomicAdd(out, s4 * (-1.0f / (float)kBatch));
    }
}

extern "C" void kernel_launch(void* const* d_in, const int* in_sizes, int n_in,
                              void* d_out, int out_size, void* d_ws, size_t ws_size,
                              hipStream_t stream) {
    const float* tw = (const float*)d_in[0];
    const float* cw = (const float*)d_in[1];
    const int*   t  = (const int*)d_in[2];
    const int*   c  = (const int*)d_in[3];
    const int*   n  = (const int*)d_in[4];
    float* out = (float*)d_out;

    // d_out is re-poisoned to 0xAA before every launch; zero it ourselves.
    hipMemsetAsync(out, 0, sizeof(float), stream);

    // 65536 samples x 32 lanes = 8192 blocks x 256 threads.
    sgns_loss_kernel<<<8192, 256, 0, stream>>>(tw, cw, t, c, n, out);
}

// Round 6
// 162.344 us; speedup vs baseline: 1.4295x; 1.3580x over previous
//
#include <hip/hip_runtime.h>
#include <hip/hip_bf16.h>

constexpr int kEmbed  = 128;
constexpr int kBatch  = 65536;
constexpr int kNeg    = 10;
constexpr float kEps  = 1e-10f;
constexpr int kGroups = 16384;   // 2048 blocks x 8 groups

// Round-3 structure (32 lanes/sample, 4 samples/group strided by kGroups)
// with 2-way sample interleaving: each pass loads BOTH samples' indices,
// then issues all 24 row-gathers back-to-back before any compute -> 2x
// outstanding memory per wave, index latency of pass p+1 hidden under
// pass p's compute.
__global__ __launch_bounds__(256, 2) void sgns_loss_kernel(
    const float* __restrict__ tw,
    const float* __restrict__ cw,
    const int*   __restrict__ t,
    const int*   __restrict__ c,
    const int*   __restrict__ n,
    float*       __restrict__ out)
{
    const int tid   = threadIdx.x;
    const int lane  = tid & 31;
    const int group = (blockIdx.x * blockDim.x + tid) >> 5;
    const int col   = 4 * lane;

    float acc = 0.0f;

    #pragma unroll
    for (int p = 0; p < 2; ++p) {
        const int ba = group + (2 * p + 0) * kGroups;
        const int bb = group + (2 * p + 1) * kGroups;

        // --- all indices for both samples ---
        const int ita = t[ba], ica = c[ba];
        const int itb = t[bb], icb = c[bb];
        int nia[kNeg], nib[kNeg];
        #pragma unroll
        for (int k = 0; k < kNeg; ++k) nia[k] = n[ba * kNeg + k];
        #pragma unroll
        for (int k = 0; k < kNeg; ++k) nib[k] = n[bb * kNeg + k];

        // --- issue the 6 "hot" gathers (vt, vc for both) ---
        const float4 vta = *reinterpret_cast<const float4*>(tw + (size_t)ita * kEmbed + col);
        const float4 vtb = *reinterpret_cast<const float4*>(tw + (size_t)itb * kEmbed + col);
        const float4 vca = *reinterpret_cast<const float4*>(cw + (size_t)ica * kEmbed + col);
        const float4 vcb = *reinterpret_cast<const float4*>(cw + (size_t)icb * kEmbed + col);

        float sa[kNeg + 1], sb[kNeg + 1];
        sa[0] = vta.x*vca.x + vta.y*vca.y + vta.z*vca.z + vta.w*vca.w;
        sb[0] = vtb.x*vcb.x + vtb.y*vcb.y + vtb.z*vcb.z + vtb.w*vcb.w;

        // --- 20 negative-row gathers, interleaved across the two samples ---
        #pragma unroll
        for (int k = 0; k < kNeg; ++k) {
            const float4 va = *reinterpret_cast<const float4*>(
                cw + (size_t)nia[k] * kEmbed + col);
            const float4 vb = *reinterpret_cast<const float4*>(
                cw + (size_t)nib[k] * kEmbed + col);
            sa[k + 1] = vta.x*va.x + vta.y*va.y + vta.z*va.z + vta.w*va.w;
            sb[k + 1] = vtb.x*vb.x + vtb.y*vb.y + vtb.z*vb.z + vtb.w*vb.w;
        }

        // --- butterfly reductions (32-lane group) ---
        #pragma unroll
        for (int k = 0; k < kNeg + 1; ++k) {
            float va = sa[k], vb = sb[k];
            va += __shfl_xor(va, 16);  vb += __shfl_xor(vb, 16);
            va += __shfl_xor(va, 8);   vb += __shfl_xor(vb, 8);
            va += __shfl_xor(va, 4);   vb += __shfl_xor(vb, 4);
            va += __shfl_xor(va, 2);   vb += __shfl_xor(vb, 2);
            va += __shfl_xor(va, 1);   vb += __shfl_xor(vb, 1);
            sa[k] = va; sb[k] = vb;
        }

        // --- log-sigmoid terms ---
        float lb = __logf(1.0f / (1.0f + __expf(-sa[0])) + kEps)
                 + __logf(1.0f / (1.0f + __expf(-sb[0])) + kEps);
        #pragma unroll
        for (int k = 1; k < kNeg + 1; ++k) {
            lb += __logf(1.0f / (1.0f + __expf(sa[k])) + kEps);
            lb += __logf(1.0f / (1.0f + __expf(sb[k])) + kEps);
        }
        if (lane == 0) acc += lb;
    }

    // Block reduction: 64-lane butterfly, then LDS across the 4 waves.
    #pragma unroll
    for (int m = 32; m >= 1; m >>= 1) acc += __shfl_xor(acc, m);

    __shared__ float wave_sum[4];
    if ((tid & 63) == 0) wave_sum[tid >> 6] = acc;
    __syncthreads();
    if (tid == 0) {
        const float s4 = wave_sum[0] + wave_sum[1] + wave_sum[2] + wave_sum[3];
        atomicAdd(out, s4 * (-1.0f / (float)kBatch));
    }
}

extern "C" void kernel_launch(void* const* d_in, const int* in_sizes, int n_in,
                              void* d_out, int out_size, void* d_ws, size_t ws_size,
                              hipStream_t stream) {
    const float* tw = (const float*)d_in[0];
    const float* cw = (const float*)d_in[1];
    const int*   t  = (const int*)d_in[2];
    const int*   c  = (const int*)d_in[3];
    const int*   n  = (const int*)d_in[4];
    float* out = (float*)d_out;

    // d_out is re-poisoned to 0xAA before every launch; zero it ourselves.
    hipMemsetAsync(out, 0, sizeof(float), stream);

    // 2048 blocks x 256 threads = 16384 groups x 4 samples (2 passes of 2).
    sgns_loss_kernel<<<2048, 256, 0, stream>>>(tw, cw, t, c, n, out);
}